// Round 16
// baseline (294.967 us; speedup 1.0000x reference)
//
#include <hip/hip_runtime.h>

#define N_TOK 131072
#define D_IN  512
#define GHID  64
#define E_EXP 16
#define CAPE  8192
#define H_DIM 128
#define O_DIM 512

typedef __attribute__((ext_vector_type(8))) short bf16x8;
typedef __attribute__((ext_vector_type(4))) short bf16x4;
typedef __attribute__((ext_vector_type(4))) float f32x4;

__device__ __forceinline__ ushort f2bf(float f) {
    uint u = __builtin_bit_cast(uint, f);
    u = u + 0x7FFFu + ((u >> 16) & 1u);   // RNE
    return (ushort)(u >> 16);
}
__device__ __forceinline__ float bf2f(ushort s) {
    return __builtin_bit_cast(float, ((uint)s) << 16);
}

// ---------------- wpack_all: one launch packs WgF, W1F, W2F and zeroes blockCounts ----------------
__global__ __launch_bounds__(64) void wpack_all(
    const float* __restrict__ Wg1, ushort* __restrict__ WgF,
    const float* __restrict__ W1,  ushort* __restrict__ W1F,
    const float* __restrict__ W2,  ushort* __restrict__ W2F,
    int* __restrict__ blockCounts)
{
    int lane = threadIdx.x;
    int bid = blockIdx.x;
    if (bid < 64) {
        blockCounts[bid * 64 + lane] = 0;    // 4096 ints
        int kc = bid >> 2, fj = bid & 3;
        int col = fj * 16 + (lane & 15);
        int k0 = kc * 32 + (lane >> 4) * 8;
        union { bf16x8 v; ushort u[8]; } p0, p1, p2;
        #pragma unroll
        for (int q = 0; q < 8; ++q) {
            float v = Wg1[(size_t)(k0 + q) * GHID + col];
            ushort s0 = f2bf(v); float r1 = v - bf2f(s0);
            ushort s1 = f2bf(r1); float r2 = r1 - bf2f(s1);
            p0.u[q] = s0; p1.u[q] = s1; p2.u[q] = f2bf(r2);
        }
        ushort* dst = WgF + (size_t)((kc * 4 + fj) * 3) * 512 + lane * 8;
        *reinterpret_cast<bf16x8*>(dst)        = p0.v;
        *reinterpret_cast<bf16x8*>(dst + 512)  = p1.v;
        *reinterpret_cast<bf16x8*>(dst + 1024) = p2.v;
    } else if (bid < 2112) {
        int b = bid - 64;
        int e = b >> 7, wid = (b >> 4) & 7, kt = b & 15;
        int h  = wid * 16 + (lane & 15);
        int k0 = kt * 32 + (lane >> 4) * 8;
        union { bf16x8 v; ushort u[8]; } p;
        #pragma unroll
        for (int q = 0; q < 8; ++q)
            p.u[q] = f2bf(W1[((size_t)e * D_IN + k0 + q) * H_DIM + h]);
        *reinterpret_cast<bf16x8*>(W1F + ((size_t)(e * 8 + wid) * 16 + kt) * 512 + lane * 8) = p.v;
    } else {
        int b = bid - 2112;
        int e = b >> 7, wid = (b >> 4) & 7, fj = (b >> 2) & 3, kt = b & 3;
        int o  = wid * 64 + fj * 16 + (lane & 15);
        int k0 = kt * 32 + (lane >> 4) * 8;
        union { bf16x8 v; ushort u[8]; } p;
        #pragma unroll
        for (int q = 0; q < 8; ++q)
            p.u[q] = f2bf(W2[((size_t)e * H_DIM + k0 + q) * O_DIM + o]);
        *reinterpret_cast<bf16x8*>(W2F + (((size_t)(e * 8 + wid) * 4 + fj) * 4 + kt) * 512 + lane * 8) = p.v;
    }
}

// One K-chunk of gating layer-1: split + 6-term MFMA. Arithmetic identical to R7-R15.
__device__ __forceinline__ void gate_step(
    const float4& x0, const float4& x1, const float4& x2, const float4& x3,
    int kc, const ushort* __restrict__ wg_lane,     // = WgF + lane*8
    f32x4 (&acc)[2][4])
{
    union U { bf16x8 v; ushort u[8]; };
    U p0[2], p1[2], p2[2];
    float f0[8] = {x0.x, x0.y, x0.z, x0.w, x1.x, x1.y, x1.z, x1.w};
    float f1[8] = {x2.x, x2.y, x2.z, x2.w, x3.x, x3.y, x3.z, x3.w};
    #pragma unroll
    for (int q = 0; q < 8; ++q) {
        float v = f0[q];
        ushort s0 = f2bf(v); float r1 = v - bf2f(s0);
        ushort s1 = f2bf(r1); float r2 = r1 - bf2f(s1);
        p0[0].u[q] = s0; p1[0].u[q] = s1; p2[0].u[q] = f2bf(r2);
    }
    #pragma unroll
    for (int q = 0; q < 8; ++q) {
        float v = f1[q];
        ushort s0 = f2bf(v); float r1 = v - bf2f(s0);
        ushort s1 = f2bf(r1); float r2 = r1 - bf2f(s1);
        p0[1].u[q] = s0; p1[1].u[q] = s1; p2[1].u[q] = f2bf(r2);
    }
    #pragma unroll
    for (int fj = 0; fj < 4; ++fj) {
        const ushort* bp = wg_lane + (size_t)((kc * 4 + fj) * 3) * 512;
        bf16x8 b0 = *reinterpret_cast<const bf16x8*>(bp);
        bf16x8 b1 = *reinterpret_cast<const bf16x8*>(bp + 512);
        bf16x8 b2 = *reinterpret_cast<const bf16x8*>(bp + 1024);
        #pragma unroll
        for (int fi = 0; fi < 2; ++fi) {
            acc[fi][fj] = __builtin_amdgcn_mfma_f32_16x16x32_bf16(p0[fi].v, b0, acc[fi][fj], 0, 0, 0);
            acc[fi][fj] = __builtin_amdgcn_mfma_f32_16x16x32_bf16(p0[fi].v, b1, acc[fi][fj], 0, 0, 0);
            acc[fi][fj] = __builtin_amdgcn_mfma_f32_16x16x32_bf16(p1[fi].v, b0, acc[fi][fj], 0, 0, 0);
            acc[fi][fj] = __builtin_amdgcn_mfma_f32_16x16x32_bf16(p0[fi].v, b2, acc[fi][fj], 0, 0, 0);
            acc[fi][fj] = __builtin_amdgcn_mfma_f32_16x16x32_bf16(p1[fi].v, b1, acc[fi][fj], 0, 0, 0);
            acc[fi][fj] = __builtin_amdgcn_mfma_f32_16x16x32_bf16(p2[fi].v, b0, acc[fi][fj], 0, 0, 0);
        }
    }
}

// ---------------- K1: gating (unchanged from R15 — proven). ----------------
__global__ __launch_bounds__(256, 4) void gating_mfma_kernel(
    const float* __restrict__ x, const ushort* __restrict__ WgF,
    const float* __restrict__ bg1, const float* __restrict__ Wg2,
    const float* __restrict__ bg2, int* __restrict__ top_expert,
    int* __restrict__ blockCounts)
{
    __shared__ float hs[128][33];        // 16.9 KB
    __shared__ int   cnt[16];

    const int tid  = threadIdx.x;
    const int lane = tid & 63, w = tid >> 6;
    const int l15  = lane & 15, l4 = lane >> 4;
    const int tile = blockIdx.x * 128 + w * 32;

    if (tid < 16) cnt[tid] = 0;

    const float4* xr0 = reinterpret_cast<const float4*>(x) + (size_t)(tile + l15) * 128 + l4 * 2;
    const float4* xr1 = xr0 + (size_t)16 * 128;

    const ushort* wg_lane = WgF + lane * 8;

    f32x4 acc[2][4] = {};   // [fi][fj]

    float4 c0 = xr0[0], c1 = xr0[1], c2 = xr1[0], c3 = xr1[1];
    #pragma unroll 2
    for (int kc = 0; kc < 16; ++kc) {
        float4 n0 = c0, n1 = c1, n2 = c2, n3 = c3;
        if (kc < 15) {
            n0 = xr0[(kc + 1) * 8];     n1 = xr0[(kc + 1) * 8 + 1];
            n2 = xr1[(kc + 1) * 8];     n3 = xr1[(kc + 1) * 8 + 1];
        }
        __builtin_amdgcn_sched_barrier(0);
        gate_step(c0, c1, c2, c3, kc, wg_lane, acc);
        __builtin_amdgcn_sched_barrier(0);
        c0 = n0; c1 = n1; c2 = n2; c3 = n3;
    }

    // ---- bias + relu in regs ----
    float bg1v[4];
    #pragma unroll
    for (int fj = 0; fj < 4; ++fj) bg1v[fj] = bg1[fj * 16 + l15];
    #pragma unroll
    for (int fi = 0; fi < 2; ++fi)
        #pragma unroll
        for (int fj = 0; fj < 4; ++fj)
            #pragma unroll
            for (int j = 0; j < 4; ++j) {
                float v = acc[fi][fj][j] + bg1v[fj];
                acc[fi][fj][j] = v > 0.f ? v : 0.f;
            }

    float lacc[16];
    #pragma unroll
    for (int e = 0; e < 16; ++e) lacc[e] = bg2[e];

    // ---- layer 2 in two half-passes (k 0..31 then 32..63), PROVEN order preserved ----
    #pragma unroll
    for (int half = 0; half < 2; ++half) {
        if (half == 1) __syncthreads();
        #pragma unroll
        for (int fj = 0; fj < 2; ++fj) {
            int fjj = half * 2 + fj;
            #pragma unroll
            for (int fi = 0; fi < 2; ++fi)
                #pragma unroll
                for (int j = 0; j < 4; ++j) {
                    int row = w * 32 + fi * 16 + l4 * 4 + j;
                    hs[row][fj * 16 + l15] = acc[fi][fjj][j];
                }
        }
        __syncthreads();
        if (tid < 128) {
            #pragma unroll 8
            for (int k = 0; k < 32; ++k) {
                float hv = hs[tid][k];
                int kk = half * 32 + k;
                #pragma unroll
                for (int e = 0; e < 16; ++e) lacc[e] += hv * Wg2[kk * 16 + e];
            }
        }
    }

    if (tid < 128) {
        float best = lacc[0]; int be = 0;
        #pragma unroll
        for (int e = 1; e < 16; ++e) {
            if (lacc[e] > best) { best = lacc[e]; be = e; }
        }
        top_expert[blockIdx.x * 128 + tid] = be;
        atomicAdd(&cnt[be], 1);
    }
    __syncthreads();
    if (tid < 16) atomicAdd(&blockCounts[(blockIdx.x >> 2) * 16 + tid], cnt[tid]);
}

// ---------------- scan + scatter ----------------
__global__ void scan_kernel(const int* __restrict__ blockCounts,
                            int* __restrict__ blockOffs, int* __restrict__ totals,
                            int* __restrict__ dropCount)
{
    int e = threadIdx.x;
    if (e == 0) *dropCount = 0;
    if (e < 16) {
        int run = 0;
        for (int b = 0; b < 256; ++b) {
            blockOffs[b * 16 + e] = run;
            run += blockCounts[b * 16 + e];
        }
        totals[e] = run;
    }
}

__global__ __launch_bounds__(64) void scatter_kernel(const int* __restrict__ te,
        const int* __restrict__ blockOffs, int* __restrict__ slot_token,
        int* __restrict__ dropCount, int* __restrict__ dropList)
{
    const int b = blockIdx.x;
    const int lane = threadIdx.x;
    int running[16];
    #pragma unroll
    for (int e = 0; e < 16; ++e) running[e] = blockOffs[b * 16 + e];
    const unsigned long long lt = (lane == 0) ? 0ull : ((~0ull) >> (64 - lane));
    const int base = b * 512;
    for (int g = 0; g < 8; ++g) {
        int n = base + g * 64 + lane;
        int e = te[n];
        int p = 0;
        #pragma unroll
        for (int ee = 0; ee < 16; ++ee) {
            unsigned long long bal = __ballot(e == ee);
            if (e == ee) p = running[ee] + __popcll(bal & lt);
            running[ee] += __popcll(bal);
        }
        if (p < CAPE) {
            slot_token[e * CAPE + p] = n;
        } else {
            int di = atomicAdd(dropCount, 1);
            dropList[di] = n;
        }
    }
}

// ---------------- K4: per-expert MLP + softmax; 32-token blocks (32 KB LDS -> 3-4 blocks/CU) ----------------
__global__ __launch_bounds__(512, 4) void expert_mfma_kernel(
    const float* __restrict__ x,
    const ushort* __restrict__ W1F, const float* __restrict__ b1,
    const ushort* __restrict__ W2F, const float* __restrict__ b2,
    const int* __restrict__ slot_token, const int* __restrict__ totals,
    float* __restrict__ out)
{
    __shared__ ushort xs_u[32 * 512];   // 32 KB; h overlays after phase 1
    __shared__ int    toks[32];
    __shared__ float  redm[8][32];
    __shared__ float  reds[8][32];

    const int tid  = threadIdx.x;
    const int e    = blockIdx.x >> 8;       // 256 blocks/expert
    const int sb   = blockIdx.x & 255;
    const int slot0 = sb * 32;
    int vc = totals[e]; if (vc > CAPE) vc = CAPE;
    if (slot0 >= vc) return;
    int nt = vc - slot0; if (nt > 32) nt = 32;

    const int lane = tid & 63;
    const int wid  = tid >> 6;
    const int l15  = lane & 15;
    const int l4   = lane >> 4;

    if (tid < 32) toks[tid] = (tid < nt) ? slot_token[e * CAPE + slot0 + tid] : -1;
    __syncthreads();

    char* xsb = (char*)xs_u;

    // ---- stage: two half-row contiguous 16B/lane loads -> swizzled bf16 LDS (32 rows) ----
    {
        float4 ga[4], gb[4];
        #pragma unroll
        for (int it = 0; it < 4; ++it) {
            int g = it * 512 + tid;            // 0..2047
            int row = g >> 6, c = g & 63;
            int tk = toks[row];
            float4 z = make_float4(0.f, 0.f, 0.f, 0.f);
            if (tk >= 0) {
                const float* xrow = &x[(size_t)tk * D_IN];
                ga[it] = *reinterpret_cast<const float4*>(xrow + c * 4);
                gb[it] = *reinterpret_cast<const float4*>(xrow + 256 + c * 4);
            } else { ga[it] = z; gb[it] = z; }
        }
        __builtin_amdgcn_sched_barrier(0);
        #pragma unroll
        for (int it = 0; it < 4; ++it) {
            int g = it * 512 + tid;
            int row = g >> 6, c = g & 63;
            int swz = (row & 7) << 4;
            union { bf16x4 v; ushort u[4]; } wa, wb;
            wa.u[0] = f2bf(ga[it].x); wa.u[1] = f2bf(ga[it].y);
            wa.u[2] = f2bf(ga[it].z); wa.u[3] = f2bf(ga[it].w);
            wb.u[0] = f2bf(gb[it].x); wb.u[1] = f2bf(gb[it].y);
            wb.u[2] = f2bf(gb[it].z); wb.u[3] = f2bf(gb[it].w);
            *reinterpret_cast<bf16x4*>(xsb + row * 1024 + ((c * 8) ^ swz))       = wa.v;
            *reinterpret_cast<bf16x4*>(xsb + row * 1024 + ((512 + c * 8) ^ swz)) = wb.v;
        }
    }
    __syncthreads();

    // ---- phase 1: h = relu(x @ W1 + b1); wave = 32 rows x 16 cols ----
    f32x4 acc1[2] = {};
    {
        const ushort* w1l = W1F + (size_t)(e * 8 + wid) * 16 * 512 + lane * 8;
        bf16x8 bcur = *reinterpret_cast<const bf16x8*>(w1l);
        #pragma unroll 4
        for (int kt = 0; kt < 16; ++kt) {
            bf16x8 bnxt = bcur;
            if (kt + 1 < 16) bnxt = *reinterpret_cast<const bf16x8*>(w1l + (kt + 1) * 512);
            __builtin_amdgcn_sched_barrier(0);
            #pragma unroll
            for (int fi = 0; fi < 2; ++fi) {
                int r = fi * 16 + l15;
                bf16x8 a = *reinterpret_cast<const bf16x8*>(xsb + r * 1024 + ((kt * 64 + l4 * 16) ^ ((r & 7) << 4)));
                acc1[fi] = __builtin_amdgcn_mfma_f32_16x16x32_bf16(a, bcur, acc1[fi], 0, 0, 0);
            }
            bcur = bnxt;
        }
    }
    __syncthreads();

    {
        int col = wid * 16 + l15;
        float bv = b1[e * H_DIM + col];
        #pragma unroll
        for (int fi = 0; fi < 2; ++fi) {
            #pragma unroll
            for (int j = 0; j < 4; ++j) {
                int row = fi * 16 + l4 * 4 + j;
                float v = acc1[fi][j] + bv;
                v = v > 0.f ? v : 0.f;
                *reinterpret_cast<ushort*>(xsb + row * 256 + ((col * 2) ^ ((row & 7) << 4))) = f2bf(v);
            }
        }
    }
    __syncthreads();

    // ---- phase 2: logits = h @ W2 + b2; wave = 32 rows x 64 cols ----
    f32x4 acc2[2][4] = {};
    {
        const ushort* w2l = W2F + (size_t)(e * 8 + wid) * 16 * 512 + lane * 8;
        #pragma unroll
        for (int kt = 0; kt < 4; ++kt) {
            bf16x8 a[2];
            #pragma unroll
            for (int fi = 0; fi < 2; ++fi) {
                int r = fi * 16 + l15;
                a[fi] = *reinterpret_cast<const bf16x8*>(xsb + r * 256 + ((kt * 64 + l4 * 16) ^ ((r & 7) << 4)));
            }
            #pragma unroll
            for (int fj = 0; fj < 4; ++fj) {
                bf16x8 bfrag = *reinterpret_cast<const bf16x8*>(w2l + (size_t)(fj * 4 + kt) * 512);
                #pragma unroll
                for (int fi = 0; fi < 2; ++fi)
                    acc2[fi][fj] = __builtin_amdgcn_mfma_f32_16x16x32_bf16(a[fi], bfrag, acc2[fi][fj], 0, 0, 0);
            }
        }
    }
    #pragma unroll
    for (int fj = 0; fj < 4; ++fj) {
        float bv = b2[e * O_DIM + wid * 64 + fj * 16 + l15];
        #pragma unroll
        for (int fi = 0; fi < 2; ++fi)
            #pragma unroll
            for (int j = 0; j < 4; ++j) acc2[fi][fj][j] += bv;
    }

    // ---- softmax over 512 cols (8 waves hold 64 each) ----
    #pragma unroll
    for (int fi = 0; fi < 2; ++fi)
        #pragma unroll
        for (int j = 0; j < 4; ++j) {
            float m = acc2[fi][0][j];
            #pragma unroll
            for (int fj = 1; fj < 4; ++fj) m = fmaxf(m, acc2[fi][fj][j]);
            #pragma unroll
            for (int msk = 1; msk < 16; msk <<= 1) m = fmaxf(m, __shfl_xor(m, msk, 64));
            if (l15 == 0) redm[wid][fi * 16 + l4 * 4 + j] = m;
        }
    __syncthreads();
    #pragma unroll
    for (int fi = 0; fi < 2; ++fi)
        #pragma unroll
        for (int j = 0; j < 4; ++j) {
            int r = fi * 16 + l4 * 4 + j;
            float M = redm[0][r];
            #pragma unroll
            for (int w = 1; w < 8; ++w) M = fmaxf(M, redm[w][r]);
            float s = 0.f;
            #pragma unroll
            for (int fj = 0; fj < 4; ++fj) {
                float ex = expf(acc2[fi][fj][j] - M);
                acc2[fi][fj][j] = ex;
                s += ex;
            }
            #pragma unroll
            for (int msk = 1; msk < 16; msk <<= 1) s += __shfl_xor(s, msk, 64);
            if (l15 == 0) reds[wid][r] = s;
        }
    __syncthreads();

    // ---- direct-store epilogue (same ex*inv bits) ----
    #pragma unroll
    for (int fi = 0; fi < 2; ++fi)
        #pragma unroll
        for (int j = 0; j < 4; ++j) {
            int r = fi * 16 + l4 * 4 + j;
            int tk = toks[r];
            if (tk < 0) continue;
            float S = reds[0][r];
            #pragma unroll
            for (int w = 1; w < 8; ++w) S += reds[w][r];
            float inv = 1.f / S;
            float* orow = out + (size_t)tk * O_DIM + wid * 64 + l15;
            #pragma unroll
            for (int fj = 0; fj < 4; ++fj) orow[fj * 16] = acc2[fi][fj][j] * inv;
        }
}

// ---------------- K5: zero rows of dropped tokens ----------------
__global__ __launch_bounds__(256) void zero_dropped_kernel(const int* __restrict__ dropCount,
        const int* __restrict__ dropList, float* __restrict__ out)
{
    int cnt = *dropCount;
    for (int i = blockIdx.x; i < cnt; i += gridDim.x) {
        int n = dropList[i];
        reinterpret_cast<float2*>(&out[(size_t)n * O_DIM])[threadIdx.x] = make_float2(0.f, 0.f);
    }
}

extern "C" void kernel_launch(void* const* d_in, const int* in_sizes, int n_in,
                              void* d_out, int out_size, void* d_ws, size_t ws_size,
                              hipStream_t stream) {
    (void)in_sizes; (void)n_in; (void)out_size; (void)ws_size;
    const float* x   = (const float*)d_in[0];
    const float* Wg1 = (const float*)d_in[1];
    const float* bg1 = (const float*)d_in[2];
    const float* Wg2 = (const float*)d_in[3];
    const float* bg2 = (const float*)d_in[4];
    const float* W1  = (const float*)d_in[5];
    const float* b1  = (const float*)d_in[6];
    const float* W2  = (const float*)d_in[7];
    const float* b2  = (const float*)d_in[8];
    float* out = (float*)d_out;

    char* ws = (char*)d_ws;
    size_t off = 0;
    int* dropCount   = (int*)(ws + off); off += 256;
    int* top_expert  = (int*)(ws + off); off += (size_t)N_TOK * 4;
    int* blockCounts = (int*)(ws + off); off += 256 * 16 * 4;
    int* blockOffs   = (int*)(ws + off); off += 256 * 16 * 4;
    int* totals      = (int*)(ws + off); off += 256;
    int* slot_token  = (int*)(ws + off); off += (size_t)E_EXP * CAPE * 4;
    int* dropList    = (int*)(ws + off); off += (size_t)N_TOK * 4;
    ushort* W1F      = (ushort*)(ws + off); off += (size_t)E_EXP * D_IN * H_DIM * 2;
    ushort* W2F      = (ushort*)(ws + off); off += (size_t)E_EXP * H_DIM * O_DIM * 2;
    ushort* WgF      = (ushort*)(ws + off); off += (size_t)3 * GHID * D_IN * 2;

    wpack_all<<<4160, 64, 0, stream>>>(Wg1, WgF, W1, W1F, W2, W2F, blockCounts);
    gating_mfma_kernel<<<N_TOK / 128, 256, 0, stream>>>(x, WgF, bg1, Wg2, bg2, top_expert, blockCounts);
    scan_kernel<<<1, 64, 0, stream>>>(blockCounts, blockOffs, totals, dropCount);
    scatter_kernel<<<N_TOK / 512, 64, 0, stream>>>(top_expert, blockOffs, slot_token, dropCount, dropList);
    expert_mfma_kernel<<<E_EXP * (CAPE / 32), 512, 0, stream>>>(x, W1F, b1, W2F, b2, slot_token, totals, out);
    zero_dropped_kernel<<<256, 256, 0, stream>>>(dropCount, dropList, out);
}

// Round 17
// 236.365 us; speedup vs baseline: 1.2479x; 1.2479x over previous
//
#include <hip/hip_runtime.h>

#define N_TOK 131072
#define D_IN  512
#define GHID  64
#define E_EXP 16
#define CAPE  8192
#define H_DIM 128
#define O_DIM 512

typedef __attribute__((ext_vector_type(8))) short bf16x8;
typedef __attribute__((ext_vector_type(4))) short bf16x4;
typedef __attribute__((ext_vector_type(4))) float f32x4;

__device__ __forceinline__ ushort f2bf(float f) {
    uint u = __builtin_bit_cast(uint, f);
    u = u + 0x7FFFu + ((u >> 16) & 1u);   // RNE
    return (ushort)(u >> 16);
}
__device__ __forceinline__ float bf2f(ushort s) {
    return __builtin_bit_cast(float, ((uint)s) << 16);
}

// ---------------- wpack_all: one launch packs WgF, W1F, W2F and zeroes blockCounts ----------------
__global__ __launch_bounds__(64) void wpack_all(
    const float* __restrict__ Wg1, ushort* __restrict__ WgF,
    const float* __restrict__ W1,  ushort* __restrict__ W1F,
    const float* __restrict__ W2,  ushort* __restrict__ W2F,
    int* __restrict__ blockCounts)
{
    int lane = threadIdx.x;
    int bid = blockIdx.x;
    if (bid < 64) {
        blockCounts[bid * 64 + lane] = 0;    // 4096 ints
        int kc = bid >> 2, fj = bid & 3;
        int col = fj * 16 + (lane & 15);
        int k0 = kc * 32 + (lane >> 4) * 8;
        union { bf16x8 v; ushort u[8]; } p0, p1, p2;
        #pragma unroll
        for (int q = 0; q < 8; ++q) {
            float v = Wg1[(size_t)(k0 + q) * GHID + col];
            ushort s0 = f2bf(v); float r1 = v - bf2f(s0);
            ushort s1 = f2bf(r1); float r2 = r1 - bf2f(s1);
            p0.u[q] = s0; p1.u[q] = s1; p2.u[q] = f2bf(r2);
        }
        ushort* dst = WgF + (size_t)((kc * 4 + fj) * 3) * 512 + lane * 8;
        *reinterpret_cast<bf16x8*>(dst)        = p0.v;
        *reinterpret_cast<bf16x8*>(dst + 512)  = p1.v;
        *reinterpret_cast<bf16x8*>(dst + 1024) = p2.v;
    } else if (bid < 2112) {
        int b = bid - 64;
        int e = b >> 7, wid = (b >> 4) & 7, kt = b & 15;
        int h  = wid * 16 + (lane & 15);
        int k0 = kt * 32 + (lane >> 4) * 8;
        union { bf16x8 v; ushort u[8]; } p;
        #pragma unroll
        for (int q = 0; q < 8; ++q)
            p.u[q] = f2bf(W1[((size_t)e * D_IN + k0 + q) * H_DIM + h]);
        *reinterpret_cast<bf16x8*>(W1F + ((size_t)(e * 8 + wid) * 16 + kt) * 512 + lane * 8) = p.v;
    } else {
        int b = bid - 2112;
        int e = b >> 7, wid = (b >> 4) & 7, fj = (b >> 2) & 3, kt = b & 3;
        int o  = wid * 64 + fj * 16 + (lane & 15);
        int k0 = kt * 32 + (lane >> 4) * 8;
        union { bf16x8 v; ushort u[8]; } p;
        #pragma unroll
        for (int q = 0; q < 8; ++q)
            p.u[q] = f2bf(W2[((size_t)e * H_DIM + k0 + q) * O_DIM + o]);
        *reinterpret_cast<bf16x8*>(W2F + (((size_t)(e * 8 + wid) * 4 + fj) * 4 + kt) * 512 + lane * 8) = p.v;
    }
}

// One K-chunk of gating layer-1: split + 6-term MFMA. Arithmetic identical to R7-R16.
__device__ __forceinline__ void gate_step(
    const float4& x0, const float4& x1, const float4& x2, const float4& x3,
    int kc, const ushort* __restrict__ wg_lane,     // = WgF + lane*8
    f32x4 (&acc)[2][4])
{
    union U { bf16x8 v; ushort u[8]; };
    U p0[2], p1[2], p2[2];
    float f0[8] = {x0.x, x0.y, x0.z, x0.w, x1.x, x1.y, x1.z, x1.w};
    float f1[8] = {x2.x, x2.y, x2.z, x2.w, x3.x, x3.y, x3.z, x3.w};
    #pragma unroll
    for (int q = 0; q < 8; ++q) {
        float v = f0[q];
        ushort s0 = f2bf(v); float r1 = v - bf2f(s0);
        ushort s1 = f2bf(r1); float r2 = r1 - bf2f(s1);
        p0[0].u[q] = s0; p1[0].u[q] = s1; p2[0].u[q] = f2bf(r2);
    }
    #pragma unroll
    for (int q = 0; q < 8; ++q) {
        float v = f1[q];
        ushort s0 = f2bf(v); float r1 = v - bf2f(s0);
        ushort s1 = f2bf(r1); float r2 = r1 - bf2f(s1);
        p0[1].u[q] = s0; p1[1].u[q] = s1; p2[1].u[q] = f2bf(r2);
    }
    #pragma unroll
    for (int fj = 0; fj < 4; ++fj) {
        const ushort* bp = wg_lane + (size_t)((kc * 4 + fj) * 3) * 512;
        bf16x8 b0 = *reinterpret_cast<const bf16x8*>(bp);
        bf16x8 b1 = *reinterpret_cast<const bf16x8*>(bp + 512);
        bf16x8 b2 = *reinterpret_cast<const bf16x8*>(bp + 1024);
        #pragma unroll
        for (int fi = 0; fi < 2; ++fi) {
            acc[fi][fj] = __builtin_amdgcn_mfma_f32_16x16x32_bf16(p0[fi].v, b0, acc[fi][fj], 0, 0, 0);
            acc[fi][fj] = __builtin_amdgcn_mfma_f32_16x16x32_bf16(p0[fi].v, b1, acc[fi][fj], 0, 0, 0);
            acc[fi][fj] = __builtin_amdgcn_mfma_f32_16x16x32_bf16(p1[fi].v, b0, acc[fi][fj], 0, 0, 0);
            acc[fi][fj] = __builtin_amdgcn_mfma_f32_16x16x32_bf16(p0[fi].v, b2, acc[fi][fj], 0, 0, 0);
            acc[fi][fj] = __builtin_amdgcn_mfma_f32_16x16x32_bf16(p1[fi].v, b1, acc[fi][fj], 0, 0, 0);
            acc[fi][fj] = __builtin_amdgcn_mfma_f32_16x16x32_bf16(p2[fi].v, b0, acc[fi][fj], 0, 0, 0);
        }
    }
}

// ---------------- K1: gating (unchanged from R15 — proven). ----------------
__global__ __launch_bounds__(256, 4) void gating_mfma_kernel(
    const float* __restrict__ x, const ushort* __restrict__ WgF,
    const float* __restrict__ bg1, const float* __restrict__ Wg2,
    const float* __restrict__ bg2, int* __restrict__ top_expert,
    int* __restrict__ blockCounts)
{
    __shared__ float hs[128][33];        // 16.9 KB
    __shared__ int   cnt[16];

    const int tid  = threadIdx.x;
    const int lane = tid & 63, w = tid >> 6;
    const int l15  = lane & 15, l4 = lane >> 4;
    const int tile = blockIdx.x * 128 + w * 32;

    if (tid < 16) cnt[tid] = 0;

    const float4* xr0 = reinterpret_cast<const float4*>(x) + (size_t)(tile + l15) * 128 + l4 * 2;
    const float4* xr1 = xr0 + (size_t)16 * 128;

    const ushort* wg_lane = WgF + lane * 8;

    f32x4 acc[2][4] = {};   // [fi][fj]

    float4 c0 = xr0[0], c1 = xr0[1], c2 = xr1[0], c3 = xr1[1];
    #pragma unroll 2
    for (int kc = 0; kc < 16; ++kc) {
        float4 n0 = c0, n1 = c1, n2 = c2, n3 = c3;
        if (kc < 15) {
            n0 = xr0[(kc + 1) * 8];     n1 = xr0[(kc + 1) * 8 + 1];
            n2 = xr1[(kc + 1) * 8];     n3 = xr1[(kc + 1) * 8 + 1];
        }
        __builtin_amdgcn_sched_barrier(0);
        gate_step(c0, c1, c2, c3, kc, wg_lane, acc);
        __builtin_amdgcn_sched_barrier(0);
        c0 = n0; c1 = n1; c2 = n2; c3 = n3;
    }

    // ---- bias + relu in regs ----
    float bg1v[4];
    #pragma unroll
    for (int fj = 0; fj < 4; ++fj) bg1v[fj] = bg1[fj * 16 + l15];
    #pragma unroll
    for (int fi = 0; fi < 2; ++fi)
        #pragma unroll
        for (int fj = 0; fj < 4; ++fj)
            #pragma unroll
            for (int j = 0; j < 4; ++j) {
                float v = acc[fi][fj][j] + bg1v[fj];
                acc[fi][fj][j] = v > 0.f ? v : 0.f;
            }

    float lacc[16];
    #pragma unroll
    for (int e = 0; e < 16; ++e) lacc[e] = bg2[e];

    // ---- layer 2 in two half-passes (k 0..31 then 32..63), PROVEN order preserved ----
    #pragma unroll
    for (int half = 0; half < 2; ++half) {
        if (half == 1) __syncthreads();
        #pragma unroll
        for (int fj = 0; fj < 2; ++fj) {
            int fjj = half * 2 + fj;
            #pragma unroll
            for (int fi = 0; fi < 2; ++fi)
                #pragma unroll
                for (int j = 0; j < 4; ++j) {
                    int row = w * 32 + fi * 16 + l4 * 4 + j;
                    hs[row][fj * 16 + l15] = acc[fi][fjj][j];
                }
        }
        __syncthreads();
        if (tid < 128) {
            #pragma unroll 8
            for (int k = 0; k < 32; ++k) {
                float hv = hs[tid][k];
                int kk = half * 32 + k;
                #pragma unroll
                for (int e = 0; e < 16; ++e) lacc[e] += hv * Wg2[kk * 16 + e];
            }
        }
    }

    if (tid < 128) {
        float best = lacc[0]; int be = 0;
        #pragma unroll
        for (int e = 1; e < 16; ++e) {
            if (lacc[e] > best) { best = lacc[e]; be = e; }
        }
        top_expert[blockIdx.x * 128 + tid] = be;
        atomicAdd(&cnt[be], 1);
    }
    __syncthreads();
    if (tid < 16) atomicAdd(&blockCounts[(blockIdx.x >> 2) * 16 + tid], cnt[tid]);
}

// ---------------- scan: parallel 2-level prefix (bit-identical integer sums) ----------------
__global__ __launch_bounds__(256) void scan_kernel(const int* __restrict__ blockCounts,
                                                   int* __restrict__ blockOffs,
                                                   int* __restrict__ totals)
{
    __shared__ int segsum[16][17];
    int t = threadIdx.x;             // 256
    int e = t & 15, seg = t >> 4;    // 16 segments x 16 experts
    int base = seg * 16;
    int local[16]; int run = 0;
    #pragma unroll
    for (int i = 0; i < 16; ++i) {
        local[i] = run;
        run += blockCounts[(base + i) * 16 + e];
    }
    segsum[seg][e] = run;
    __syncthreads();
    int off = 0;
    for (int s = 0; s < seg; ++s) off += segsum[s][e];
    #pragma unroll
    for (int i = 0; i < 16; ++i) blockOffs[(base + i) * 16 + e] = off + local[i];
    if (seg == 15) totals[e] = off + run;
}

// ---------------- scatter: ballot-prefix ordered placement + cooperative drop-zeroing ----------------
__global__ __launch_bounds__(64) void scatter_kernel(const int* __restrict__ te,
        const int* __restrict__ blockOffs, int* __restrict__ slot_token,
        float* __restrict__ out)
{
    const int b = blockIdx.x;
    const int lane = threadIdx.x;
    int running[16];
    #pragma unroll
    for (int e = 0; e < 16; ++e) running[e] = blockOffs[b * 16 + e];
    const unsigned long long lt = (lane == 0) ? 0ull : ((~0ull) >> (64 - lane));
    const int base = b * 512;
    for (int g = 0; g < 8; ++g) {
        int n = base + g * 64 + lane;
        int e = te[n];
        int p = 0;
        #pragma unroll
        for (int ee = 0; ee < 16; ++ee) {
            unsigned long long bal = __ballot(e == ee);
            if (e == ee) p = running[ee] + __popcll(bal & lt);
            running[ee] += __popcll(bal);
        }
        bool drop = (p >= CAPE);
        if (!drop) slot_token[e * CAPE + p] = n;
        // cooperative zeroing of dropped rows (rare)
        unsigned long long dm = __ballot(drop);
        while (dm) {
            int l = __ffsll((long long)dm) - 1;
            int nd = __shfl(n, l, 64);
            float4 z = make_float4(0.f, 0.f, 0.f, 0.f);
            reinterpret_cast<float4*>(&out[(size_t)nd * O_DIM])[lane]      = z;
            reinterpret_cast<float4*>(&out[(size_t)nd * O_DIM])[lane + 64] = z;
            dm &= dm - 1;
        }
    }
}

// ---------------- K4: per-expert MLP + softmax (R15 64-token version, verbatim) ----------------
__global__ __launch_bounds__(512, 4) void expert_mfma_kernel(
    const float* __restrict__ x,
    const ushort* __restrict__ W1F, const float* __restrict__ b1,
    const ushort* __restrict__ W2F, const float* __restrict__ b2,
    const int* __restrict__ slot_token, const int* __restrict__ totals,
    float* __restrict__ out)
{
    __shared__ ushort xs_u[64 * 512];   // 64 KB; h overlays after phase 1
    __shared__ int    toks[64];
    __shared__ float  redm[8][64];
    __shared__ float  reds[8][64];

    const int tid  = threadIdx.x;
    const int e    = blockIdx.x >> 7;
    const int sb   = blockIdx.x & 127;
    const int slot0 = sb * 64;
    int vc = totals[e]; if (vc > CAPE) vc = CAPE;
    if (slot0 >= vc) return;
    int nt = vc - slot0; if (nt > 64) nt = 64;

    const int lane = tid & 63;
    const int wid  = tid >> 6;
    const int l15  = lane & 15;
    const int l4   = lane >> 4;

    if (tid < 64) toks[tid] = (tid < nt) ? slot_token[e * CAPE + slot0 + tid] : -1;
    __syncthreads();

    char* xsb = (char*)xs_u;

    // ---- stage: two half-row contiguous 16B/lane loads -> swizzled bf16 LDS ----
    {
        float4 ga[8], gb[8];
        #pragma unroll
        for (int it = 0; it < 8; ++it) {
            int g = it * 512 + tid;
            int row = g >> 6, c = g & 63;
            int tk = toks[row];
            float4 z = make_float4(0.f, 0.f, 0.f, 0.f);
            if (tk >= 0) {
                const float* xrow = &x[(size_t)tk * D_IN];
                ga[it] = *reinterpret_cast<const float4*>(xrow + c * 4);
                gb[it] = *reinterpret_cast<const float4*>(xrow + 256 + c * 4);
            } else { ga[it] = z; gb[it] = z; }
        }
        __builtin_amdgcn_sched_barrier(0);
        #pragma unroll
        for (int it = 0; it < 8; ++it) {
            int g = it * 512 + tid;
            int row = g >> 6, c = g & 63;
            int swz = (row & 7) << 4;
            union { bf16x4 v; ushort u[4]; } wa, wb;
            wa.u[0] = f2bf(ga[it].x); wa.u[1] = f2bf(ga[it].y);
            wa.u[2] = f2bf(ga[it].z); wa.u[3] = f2bf(ga[it].w);
            wb.u[0] = f2bf(gb[it].x); wb.u[1] = f2bf(gb[it].y);
            wb.u[2] = f2bf(gb[it].z); wb.u[3] = f2bf(gb[it].w);
            *reinterpret_cast<bf16x4*>(xsb + row * 1024 + ((c * 8) ^ swz))       = wa.v;
            *reinterpret_cast<bf16x4*>(xsb + row * 1024 + ((512 + c * 8) ^ swz)) = wb.v;
        }
    }
    __syncthreads();

    f32x4 acc1[4] = {};
    {
        const ushort* w1l = W1F + (size_t)(e * 8 + wid) * 16 * 512 + lane * 8;
        bf16x8 bcur = *reinterpret_cast<const bf16x8*>(w1l);
        #pragma unroll 4
        for (int kt = 0; kt < 16; ++kt) {
            bf16x8 bnxt = bcur;
            if (kt + 1 < 16) bnxt = *reinterpret_cast<const bf16x8*>(w1l + (kt + 1) * 512);
            __builtin_amdgcn_sched_barrier(0);
            #pragma unroll
            for (int fi = 0; fi < 4; ++fi) {
                int r = fi * 16 + l15;
                bf16x8 a = *reinterpret_cast<const bf16x8*>(xsb + r * 1024 + ((kt * 64 + l4 * 16) ^ ((r & 7) << 4)));
                acc1[fi] = __builtin_amdgcn_mfma_f32_16x16x32_bf16(a, bcur, acc1[fi], 0, 0, 0);
            }
            bcur = bnxt;
        }
    }
    __syncthreads();

    {
        int col = wid * 16 + l15;
        float bv = b1[e * H_DIM + col];
        #pragma unroll
        for (int fi = 0; fi < 4; ++fi) {
            #pragma unroll
            for (int j = 0; j < 4; ++j) {
                int row = fi * 16 + l4 * 4 + j;
                float v = acc1[fi][j] + bv;
                v = v > 0.f ? v : 0.f;
                *reinterpret_cast<ushort*>(xsb + row * 256 + ((col * 2) ^ ((row & 7) << 4))) = f2bf(v);
            }
        }
    }
    __syncthreads();

    f32x4 acc2[4][4] = {};
    {
        const ushort* w2l = W2F + (size_t)(e * 8 + wid) * 16 * 512 + lane * 8;
        #pragma unroll
        for (int kt = 0; kt < 4; ++kt) {
            bf16x8 a[4];
            #pragma unroll
            for (int fi = 0; fi < 4; ++fi) {
                int r = fi * 16 + l15;
                a[fi] = *reinterpret_cast<const bf16x8*>(xsb + r * 256 + ((kt * 64 + l4 * 16) ^ ((r & 7) << 4)));
            }
            #pragma unroll
            for (int fj = 0; fj < 4; ++fj) {
                bf16x8 bfrag = *reinterpret_cast<const bf16x8*>(w2l + (size_t)(fj * 4 + kt) * 512);
                #pragma unroll
                for (int fi = 0; fi < 4; ++fi)
                    acc2[fi][fj] = __builtin_amdgcn_mfma_f32_16x16x32_bf16(a[fi], bfrag, acc2[fi][fj], 0, 0, 0);
            }
        }
    }
    #pragma unroll
    for (int fj = 0; fj < 4; ++fj) {
        float bv = b2[e * O_DIM + wid * 64 + fj * 16 + l15];
        #pragma unroll
        for (int fi = 0; fi < 4; ++fi)
            #pragma unroll
            for (int j = 0; j < 4; ++j) acc2[fi][fj][j] += bv;
    }

    #pragma unroll
    for (int fi = 0; fi < 4; ++fi)
        #pragma unroll
        for (int j = 0; j < 4; ++j) {
            float m = acc2[fi][0][j];
            #pragma unroll
            for (int fj = 1; fj < 4; ++fj) m = fmaxf(m, acc2[fi][fj][j]);
            #pragma unroll
            for (int msk = 1; msk < 16; msk <<= 1) m = fmaxf(m, __shfl_xor(m, msk, 64));
            if (l15 == 0) redm[wid][fi * 16 + l4 * 4 + j] = m;
        }
    __syncthreads();
    #pragma unroll
    for (int fi = 0; fi < 4; ++fi)
        #pragma unroll
        for (int j = 0; j < 4; ++j) {
            int r = fi * 16 + l4 * 4 + j;
            float M = redm[0][r];
            #pragma unroll
            for (int w = 1; w < 8; ++w) M = fmaxf(M, redm[w][r]);
            float s = 0.f;
            #pragma unroll
            for (int fj = 0; fj < 4; ++fj) {
                float ex = expf(acc2[fi][fj][j] - M);
                acc2[fi][fj][j] = ex;
                s += ex;
            }
            #pragma unroll
            for (int msk = 1; msk < 16; msk <<= 1) s += __shfl_xor(s, msk, 64);
            if (l15 == 0) reds[wid][r] = s;
        }
    __syncthreads();

    // ---- direct-store epilogue (same ex*inv bits) ----
    #pragma unroll
    for (int fi = 0; fi < 4; ++fi)
        #pragma unroll
        for (int j = 0; j < 4; ++j) {
            int r = fi * 16 + l4 * 4 + j;
            int tk = toks[r];
            if (tk < 0) continue;
            float S = reds[0][r];
            #pragma unroll
            for (int w = 1; w < 8; ++w) S += reds[w][r];
            float inv = 1.f / S;
            float* orow = out + (size_t)tk * O_DIM + wid * 64 + l15;
            #pragma unroll
            for (int fj = 0; fj < 4; ++fj) orow[fj * 16] = acc2[fi][fj][j] * inv;
        }
}

extern "C" void kernel_launch(void* const* d_in, const int* in_sizes, int n_in,
                              void* d_out, int out_size, void* d_ws, size_t ws_size,
                              hipStream_t stream) {
    (void)in_sizes; (void)n_in; (void)out_size; (void)ws_size;
    const float* x   = (const float*)d_in[0];
    const float* Wg1 = (const float*)d_in[1];
    const float* bg1 = (const float*)d_in[2];
    const float* Wg2 = (const float*)d_in[3];
    const float* bg2 = (const float*)d_in[4];
    const float* W1  = (const float*)d_in[5];
    const float* b1  = (const float*)d_in[6];
    const float* W2  = (const float*)d_in[7];
    const float* b2  = (const float*)d_in[8];
    float* out = (float*)d_out;

    char* ws = (char*)d_ws;
    size_t off = 0;
    int* top_expert  = (int*)(ws + off); off += (size_t)N_TOK * 4;
    int* blockCounts = (int*)(ws + off); off += 256 * 16 * 4;
    int* blockOffs   = (int*)(ws + off); off += 256 * 16 * 4;
    int* totals      = (int*)(ws + off); off += 256;
    int* slot_token  = (int*)(ws + off); off += (size_t)E_EXP * CAPE * 4;
    ushort* W1F      = (ushort*)(ws + off); off += (size_t)E_EXP * D_IN * H_DIM * 2;
    ushort* W2F      = (ushort*)(ws + off); off += (size_t)E_EXP * H_DIM * O_DIM * 2;
    ushort* WgF      = (ushort*)(ws + off); off += (size_t)3 * GHID * D_IN * 2;

    wpack_all<<<4160, 64, 0, stream>>>(Wg1, WgF, W1, W1F, W2, W2F, blockCounts);
    gating_mfma_kernel<<<N_TOK / 128, 256, 0, stream>>>(x, WgF, bg1, Wg2, bg2, top_expert, blockCounts);
    scan_kernel<<<1, 256, 0, stream>>>(blockCounts, blockOffs, totals);
    scatter_kernel<<<N_TOK / 512, 64, 0, stream>>>(top_expert, blockOffs, slot_token, out);
    expert_mfma_kernel<<<E_EXP * (CAPE / 64), 512, 0, stream>>>(x, W1F, b1, W2F, b2, slot_token, totals, out);
}

// Round 18
// 236.274 us; speedup vs baseline: 1.2484x; 1.0004x over previous
//
#include <hip/hip_runtime.h>

#define N_TOK 131072
#define D_IN  512
#define GHID  64
#define E_EXP 16
#define CAPE  8192
#define H_DIM 128
#define O_DIM 512

typedef __attribute__((ext_vector_type(8))) short bf16x8;
typedef __attribute__((ext_vector_type(4))) short bf16x4;
typedef __attribute__((ext_vector_type(4))) float f32x4;

__device__ __forceinline__ ushort f2bf(float f) {
    uint u = __builtin_bit_cast(uint, f);
    u = u + 0x7FFFu + ((u >> 16) & 1u);   // RNE
    return (ushort)(u >> 16);
}
__device__ __forceinline__ float bf2f(ushort s) {
    return __builtin_bit_cast(float, ((uint)s) << 16);
}

// ---------------- wpack_all: one launch packs WgF, W1F, W2F and zeroes blockCounts ----------------
__global__ __launch_bounds__(64) void wpack_all(
    const float* __restrict__ Wg1, ushort* __restrict__ WgF,
    const float* __restrict__ W1,  ushort* __restrict__ W1F,
    const float* __restrict__ W2,  ushort* __restrict__ W2F,
    int* __restrict__ blockCounts)
{
    int lane = threadIdx.x;
    int bid = blockIdx.x;
    if (bid < 64) {
        blockCounts[bid * 64 + lane] = 0;    // 4096 ints
        int kc = bid >> 2, fj = bid & 3;
        int col = fj * 16 + (lane & 15);
        int k0 = kc * 32 + (lane >> 4) * 8;
        union { bf16x8 v; ushort u[8]; } p0, p1, p2;
        #pragma unroll
        for (int q = 0; q < 8; ++q) {
            float v = Wg1[(size_t)(k0 + q) * GHID + col];
            ushort s0 = f2bf(v); float r1 = v - bf2f(s0);
            ushort s1 = f2bf(r1); float r2 = r1 - bf2f(s1);
            p0.u[q] = s0; p1.u[q] = s1; p2.u[q] = f2bf(r2);
        }
        ushort* dst = WgF + (size_t)((kc * 4 + fj) * 3) * 512 + lane * 8;
        *reinterpret_cast<bf16x8*>(dst)        = p0.v;
        *reinterpret_cast<bf16x8*>(dst + 512)  = p1.v;
        *reinterpret_cast<bf16x8*>(dst + 1024) = p2.v;
    } else if (bid < 2112) {
        int b = bid - 64;
        int e = b >> 7, wid = (b >> 4) & 7, kt = b & 15;
        int h  = wid * 16 + (lane & 15);
        int k0 = kt * 32 + (lane >> 4) * 8;
        union { bf16x8 v; ushort u[8]; } p;
        #pragma unroll
        for (int q = 0; q < 8; ++q)
            p.u[q] = f2bf(W1[((size_t)e * D_IN + k0 + q) * H_DIM + h]);
        *reinterpret_cast<bf16x8*>(W1F + ((size_t)(e * 8 + wid) * 16 + kt) * 512 + lane * 8) = p.v;
    } else {
        int b = bid - 2112;
        int e = b >> 7, wid = (b >> 4) & 7, fj = (b >> 2) & 3, kt = b & 3;
        int o  = wid * 64 + fj * 16 + (lane & 15);
        int k0 = kt * 32 + (lane >> 4) * 8;
        union { bf16x8 v; ushort u[8]; } p;
        #pragma unroll
        for (int q = 0; q < 8; ++q)
            p.u[q] = f2bf(W2[((size_t)e * H_DIM + k0 + q) * O_DIM + o]);
        *reinterpret_cast<bf16x8*>(W2F + (((size_t)(e * 8 + wid) * 4 + fj) * 4 + kt) * 512 + lane * 8) = p.v;
    }
}

// One K-chunk of gating layer-1: split + 6-term MFMA. Arithmetic identical to R7-R17.
__device__ __forceinline__ void gate_step(
    const float4& x0, const float4& x1, const float4& x2, const float4& x3,
    int kc, const ushort* __restrict__ wg_lane,     // = WgF + lane*8
    f32x4 (&acc)[2][4])
{
    union U { bf16x8 v; ushort u[8]; };
    U p0[2], p1[2], p2[2];
    float f0[8] = {x0.x, x0.y, x0.z, x0.w, x1.x, x1.y, x1.z, x1.w};
    float f1[8] = {x2.x, x2.y, x2.z, x2.w, x3.x, x3.y, x3.z, x3.w};
    #pragma unroll
    for (int q = 0; q < 8; ++q) {
        float v = f0[q];
        ushort s0 = f2bf(v); float r1 = v - bf2f(s0);
        ushort s1 = f2bf(r1); float r2 = r1 - bf2f(s1);
        p0[0].u[q] = s0; p1[0].u[q] = s1; p2[0].u[q] = f2bf(r2);
    }
    #pragma unroll
    for (int q = 0; q < 8; ++q) {
        float v = f1[q];
        ushort s0 = f2bf(v); float r1 = v - bf2f(s0);
        ushort s1 = f2bf(r1); float r2 = r1 - bf2f(s1);
        p0[1].u[q] = s0; p1[1].u[q] = s1; p2[1].u[q] = f2bf(r2);
    }
    #pragma unroll
    for (int fj = 0; fj < 4; ++fj) {
        const ushort* bp = wg_lane + (size_t)((kc * 4 + fj) * 3) * 512;
        bf16x8 b0 = *reinterpret_cast<const bf16x8*>(bp);
        bf16x8 b1 = *reinterpret_cast<const bf16x8*>(bp + 512);
        bf16x8 b2 = *reinterpret_cast<const bf16x8*>(bp + 1024);
        #pragma unroll
        for (int fi = 0; fi < 2; ++fi) {
            acc[fi][fj] = __builtin_amdgcn_mfma_f32_16x16x32_bf16(p0[fi].v, b0, acc[fi][fj], 0, 0, 0);
            acc[fi][fj] = __builtin_amdgcn_mfma_f32_16x16x32_bf16(p0[fi].v, b1, acc[fi][fj], 0, 0, 0);
            acc[fi][fj] = __builtin_amdgcn_mfma_f32_16x16x32_bf16(p1[fi].v, b0, acc[fi][fj], 0, 0, 0);
            acc[fi][fj] = __builtin_amdgcn_mfma_f32_16x16x32_bf16(p0[fi].v, b2, acc[fi][fj], 0, 0, 0);
            acc[fi][fj] = __builtin_amdgcn_mfma_f32_16x16x32_bf16(p1[fi].v, b1, acc[fi][fj], 0, 0, 0);
            acc[fi][fj] = __builtin_amdgcn_mfma_f32_16x16x32_bf16(p2[fi].v, b0, acc[fi][fj], 0, 0, 0);
        }
    }
}

// ---------------- K1: gating, depth-2 pinned prefetch (R15 structure otherwise). ----------------
__global__ __launch_bounds__(256, 4) void gating_mfma_kernel(
    const float* __restrict__ x, const ushort* __restrict__ WgF,
    const float* __restrict__ bg1, const float* __restrict__ Wg2,
    const float* __restrict__ bg2, int* __restrict__ top_expert,
    int* __restrict__ blockCounts)
{
    __shared__ float hs[128][33];        // 16.9 KB
    __shared__ int   cnt[16];

    const int tid  = threadIdx.x;
    const int lane = tid & 63, w = tid >> 6;
    const int l15  = lane & 15, l4 = lane >> 4;
    const int tile = blockIdx.x * 128 + w * 32;

    if (tid < 16) cnt[tid] = 0;

    const float4* xr0 = reinterpret_cast<const float4*>(x) + (size_t)(tile + l15) * 128 + l4 * 2;
    const float4* xr1 = xr0 + (size_t)16 * 128;

    const ushort* wg_lane = WgF + lane * 8;

    f32x4 acc[2][4] = {};   // [fi][fj]

    // depth-2 software pipeline: a* = chunk kc, b* = chunk kc+1; issue kc+2 during compute(kc).
    float4 a0 = xr0[0], a1 = xr0[1], a2 = xr1[0], a3 = xr1[1];
    float4 b0 = xr0[8], b1 = xr0[9], b2 = xr1[8], b3 = xr1[9];
    #pragma unroll 2
    for (int kc = 0; kc < 16; ++kc) {
        float4 m0 = b0, m1 = b1, m2 = b2, m3 = b3;
        if (kc < 14) {
            m0 = xr0[(kc + 2) * 8];     m1 = xr0[(kc + 2) * 8 + 1];
            m2 = xr1[(kc + 2) * 8];     m3 = xr1[(kc + 2) * 8 + 1];
        }
        __builtin_amdgcn_sched_barrier(0);
        gate_step(a0, a1, a2, a3, kc, wg_lane, acc);
        __builtin_amdgcn_sched_barrier(0);
        a0 = b0; a1 = b1; a2 = b2; a3 = b3;
        b0 = m0; b1 = m1; b2 = m2; b3 = m3;
    }

    // ---- bias + relu in regs ----
    float bg1v[4];
    #pragma unroll
    for (int fj = 0; fj < 4; ++fj) bg1v[fj] = bg1[fj * 16 + l15];
    #pragma unroll
    for (int fi = 0; fi < 2; ++fi)
        #pragma unroll
        for (int fj = 0; fj < 4; ++fj)
            #pragma unroll
            for (int j = 0; j < 4; ++j) {
                float v = acc[fi][fj][j] + bg1v[fj];
                acc[fi][fj][j] = v > 0.f ? v : 0.f;
            }

    float lacc[16];
    #pragma unroll
    for (int e = 0; e < 16; ++e) lacc[e] = bg2[e];

    // ---- layer 2 in two half-passes (k 0..31 then 32..63), PROVEN order preserved ----
    #pragma unroll
    for (int half = 0; half < 2; ++half) {
        if (half == 1) __syncthreads();
        #pragma unroll
        for (int fj = 0; fj < 2; ++fj) {
            int fjj = half * 2 + fj;
            #pragma unroll
            for (int fi = 0; fi < 2; ++fi)
                #pragma unroll
                for (int j = 0; j < 4; ++j) {
                    int row = w * 32 + fi * 16 + l4 * 4 + j;
                    hs[row][fj * 16 + l15] = acc[fi][fjj][j];
                }
        }
        __syncthreads();
        if (tid < 128) {
            #pragma unroll 8
            for (int k = 0; k < 32; ++k) {
                float hv = hs[tid][k];
                int kk = half * 32 + k;
                #pragma unroll
                for (int e = 0; e < 16; ++e) lacc[e] += hv * Wg2[kk * 16 + e];
            }
        }
    }

    if (tid < 128) {
        float best = lacc[0]; int be = 0;
        #pragma unroll
        for (int e = 1; e < 16; ++e) {
            if (lacc[e] > best) { best = lacc[e]; be = e; }
        }
        top_expert[blockIdx.x * 128 + tid] = be;
        atomicAdd(&cnt[be], 1);
    }
    __syncthreads();
    if (tid < 16) atomicAdd(&blockCounts[(blockIdx.x >> 2) * 16 + tid], cnt[tid]);
}

// ---------------- scan: parallel 2-level prefix (bit-identical integer sums) ----------------
__global__ __launch_bounds__(256) void scan_kernel(const int* __restrict__ blockCounts,
                                                   int* __restrict__ blockOffs,
                                                   int* __restrict__ totals)
{
    __shared__ int segsum[16][17];
    int t = threadIdx.x;             // 256
    int e = t & 15, seg = t >> 4;    // 16 segments x 16 experts
    int base = seg * 16;
    int local[16]; int run = 0;
    #pragma unroll
    for (int i = 0; i < 16; ++i) {
        local[i] = run;
        run += blockCounts[(base + i) * 16 + e];
    }
    segsum[seg][e] = run;
    __syncthreads();
    int off = 0;
    for (int s = 0; s < seg; ++s) off += segsum[s][e];
    #pragma unroll
    for (int i = 0; i < 16; ++i) blockOffs[(base + i) * 16 + e] = off + local[i];
    if (seg == 15) totals[e] = off + run;
}

// ---------------- scatter: ballot-prefix ordered placement + cooperative drop-zeroing ----------------
__global__ __launch_bounds__(64) void scatter_kernel(const int* __restrict__ te,
        const int* __restrict__ blockOffs, int* __restrict__ slot_token,
        float* __restrict__ out)
{
    const int b = blockIdx.x;
    const int lane = threadIdx.x;
    int running[16];
    #pragma unroll
    for (int e = 0; e < 16; ++e) running[e] = blockOffs[b * 16 + e];
    const unsigned long long lt = (lane == 0) ? 0ull : ((~0ull) >> (64 - lane));
    const int base = b * 512;
    for (int g = 0; g < 8; ++g) {
        int n = base + g * 64 + lane;
        int e = te[n];
        int p = 0;
        #pragma unroll
        for (int ee = 0; ee < 16; ++ee) {
            unsigned long long bal = __ballot(e == ee);
            if (e == ee) p = running[ee] + __popcll(bal & lt);
            running[ee] += __popcll(bal);
        }
        bool drop = (p >= CAPE);
        if (!drop) slot_token[e * CAPE + p] = n;
        unsigned long long dm = __ballot(drop);
        while (dm) {
            int l = __ffsll((long long)dm) - 1;
            int nd = __shfl(n, l, 64);
            float4 z = make_float4(0.f, 0.f, 0.f, 0.f);
            reinterpret_cast<float4*>(&out[(size_t)nd * O_DIM])[lane]      = z;
            reinterpret_cast<float4*>(&out[(size_t)nd * O_DIM])[lane + 64] = z;
            dm &= dm - 1;
        }
    }
}

// ---------------- K4: per-expert MLP + softmax (R15/R17 64-token version, verbatim) ----------------
__global__ __launch_bounds__(512, 4) void expert_mfma_kernel(
    const float* __restrict__ x,
    const ushort* __restrict__ W1F, const float* __restrict__ b1,
    const ushort* __restrict__ W2F, const float* __restrict__ b2,
    const int* __restrict__ slot_token, const int* __restrict__ totals,
    float* __restrict__ out)
{
    __shared__ ushort xs_u[64 * 512];   // 64 KB; h overlays after phase 1
    __shared__ int    toks[64];
    __shared__ float  redm[8][64];
    __shared__ float  reds[8][64];

    const int tid  = threadIdx.x;
    const int e    = blockIdx.x >> 7;
    const int sb   = blockIdx.x & 127;
    const int slot0 = sb * 64;
    int vc = totals[e]; if (vc > CAPE) vc = CAPE;
    if (slot0 >= vc) return;
    int nt = vc - slot0; if (nt > 64) nt = 64;

    const int lane = tid & 63;
    const int wid  = tid >> 6;
    const int l15  = lane & 15;
    const int l4   = lane >> 4;

    if (tid < 64) toks[tid] = (tid < nt) ? slot_token[e * CAPE + slot0 + tid] : -1;
    __syncthreads();

    char* xsb = (char*)xs_u;

    {
        float4 ga[8], gb[8];
        #pragma unroll
        for (int it = 0; it < 8; ++it) {
            int g = it * 512 + tid;
            int row = g >> 6, c = g & 63;
            int tk = toks[row];
            float4 z = make_float4(0.f, 0.f, 0.f, 0.f);
            if (tk >= 0) {
                const float* xrow = &x[(size_t)tk * D_IN];
                ga[it] = *reinterpret_cast<const float4*>(xrow + c * 4);
                gb[it] = *reinterpret_cast<const float4*>(xrow + 256 + c * 4);
            } else { ga[it] = z; gb[it] = z; }
        }
        __builtin_amdgcn_sched_barrier(0);
        #pragma unroll
        for (int it = 0; it < 8; ++it) {
            int g = it * 512 + tid;
            int row = g >> 6, c = g & 63;
            int swz = (row & 7) << 4;
            union { bf16x4 v; ushort u[4]; } wa, wb;
            wa.u[0] = f2bf(ga[it].x); wa.u[1] = f2bf(ga[it].y);
            wa.u[2] = f2bf(ga[it].z); wa.u[3] = f2bf(ga[it].w);
            wb.u[0] = f2bf(gb[it].x); wb.u[1] = f2bf(gb[it].y);
            wb.u[2] = f2bf(gb[it].z); wb.u[3] = f2bf(gb[it].w);
            *reinterpret_cast<bf16x4*>(xsb + row * 1024 + ((c * 8) ^ swz))       = wa.v;
            *reinterpret_cast<bf16x4*>(xsb + row * 1024 + ((512 + c * 8) ^ swz)) = wb.v;
        }
    }
    __syncthreads();

    f32x4 acc1[4] = {};
    {
        const ushort* w1l = W1F + (size_t)(e * 8 + wid) * 16 * 512 + lane * 8;
        bf16x8 bcur = *reinterpret_cast<const bf16x8*>(w1l);
        #pragma unroll 4
        for (int kt = 0; kt < 16; ++kt) {
            bf16x8 bnxt = bcur;
            if (kt + 1 < 16) bnxt = *reinterpret_cast<const bf16x8*>(w1l + (kt + 1) * 512);
            __builtin_amdgcn_sched_barrier(0);
            #pragma unroll
            for (int fi = 0; fi < 4; ++fi) {
                int r = fi * 16 + l15;
                bf16x8 a = *reinterpret_cast<const bf16x8*>(xsb + r * 1024 + ((kt * 64 + l4 * 16) ^ ((r & 7) << 4)));
                acc1[fi] = __builtin_amdgcn_mfma_f32_16x16x32_bf16(a, bcur, acc1[fi], 0, 0, 0);
            }
            bcur = bnxt;
        }
    }
    __syncthreads();

    {
        int col = wid * 16 + l15;
        float bv = b1[e * H_DIM + col];
        #pragma unroll
        for (int fi = 0; fi < 4; ++fi) {
            #pragma unroll
            for (int j = 0; j < 4; ++j) {
                int row = fi * 16 + l4 * 4 + j;
                float v = acc1[fi][j] + bv;
                v = v > 0.f ? v : 0.f;
                *reinterpret_cast<ushort*>(xsb + row * 256 + ((col * 2) ^ ((row & 7) << 4))) = f2bf(v);
            }
        }
    }
    __syncthreads();

    f32x4 acc2[4][4] = {};
    {
        const ushort* w2l = W2F + (size_t)(e * 8 + wid) * 16 * 512 + lane * 8;
        #pragma unroll
        for (int kt = 0; kt < 4; ++kt) {
            bf16x8 a[4];
            #pragma unroll
            for (int fi = 0; fi < 4; ++fi) {
                int r = fi * 16 + l15;
                a[fi] = *reinterpret_cast<const bf16x8*>(xsb + r * 256 + ((kt * 64 + l4 * 16) ^ ((r & 7) << 4)));
            }
            #pragma unroll
            for (int fj = 0; fj < 4; ++fj) {
                bf16x8 bfrag = *reinterpret_cast<const bf16x8*>(w2l + (size_t)(fj * 4 + kt) * 512);
                #pragma unroll
                for (int fi = 0; fi < 4; ++fi)
                    acc2[fi][fj] = __builtin_amdgcn_mfma_f32_16x16x32_bf16(a[fi], bfrag, acc2[fi][fj], 0, 0, 0);
            }
        }
    }
    #pragma unroll
    for (int fj = 0; fj < 4; ++fj) {
        float bv = b2[e * O_DIM + wid * 64 + fj * 16 + l15];
        #pragma unroll
        for (int fi = 0; fi < 4; ++fi)
            #pragma unroll
            for (int j = 0; j < 4; ++j) acc2[fi][fj][j] += bv;
    }

    #pragma unroll
    for (int fi = 0; fi < 4; ++fi)
        #pragma unroll
        for (int j = 0; j < 4; ++j) {
            float m = acc2[fi][0][j];
            #pragma unroll
            for (int fj = 1; fj < 4; ++fj) m = fmaxf(m, acc2[fi][fj][j]);
            #pragma unroll
            for (int msk = 1; msk < 16; msk <<= 1) m = fmaxf(m, __shfl_xor(m, msk, 64));
            if (l15 == 0) redm[wid][fi * 16 + l4 * 4 + j] = m;
        }
    __syncthreads();
    #pragma unroll
    for (int fi = 0; fi < 4; ++fi)
        #pragma unroll
        for (int j = 0; j < 4; ++j) {
            int r = fi * 16 + l4 * 4 + j;
            float M = redm[0][r];
            #pragma unroll
            for (int w = 1; w < 8; ++w) M = fmaxf(M, redm[w][r]);
            float s = 0.f;
            #pragma unroll
            for (int fj = 0; fj < 4; ++fj) {
                float ex = expf(acc2[fi][fj][j] - M);
                acc2[fi][fj][j] = ex;
                s += ex;
            }
            #pragma unroll
            for (int msk = 1; msk < 16; msk <<= 1) s += __shfl_xor(s, msk, 64);
            if (l15 == 0) reds[wid][r] = s;
        }
    __syncthreads();

    #pragma unroll
    for (int fi = 0; fi < 4; ++fi)
        #pragma unroll
        for (int j = 0; j < 4; ++j) {
            int r = fi * 16 + l4 * 4 + j;
            int tk = toks[r];
            if (tk < 0) continue;
            float S = reds[0][r];
            #pragma unroll
            for (int w = 1; w < 8; ++w) S += reds[w][r];
            float inv = 1.f / S;
            float* orow = out + (size_t)tk * O_DIM + wid * 64 + l15;
            #pragma unroll
            for (int fj = 0; fj < 4; ++fj) orow[fj * 16] = acc2[fi][fj][j] * inv;
        }
}

extern "C" void kernel_launch(void* const* d_in, const int* in_sizes, int n_in,
                              void* d_out, int out_size, void* d_ws, size_t ws_size,
                              hipStream_t stream) {
    (void)in_sizes; (void)n_in; (void)out_size; (void)ws_size;
    const float* x   = (const float*)d_in[0];
    const float* Wg1 = (const float*)d_in[1];
    const float* bg1 = (const float*)d_in[2];
    const float* Wg2 = (const float*)d_in[3];
    const float* bg2 = (const float*)d_in[4];
    const float* W1  = (const float*)d_in[5];
    const float* b1  = (const float*)d_in[6];
    const float* W2  = (const float*)d_in[7];
    const float* b2  = (const float*)d_in[8];
    float* out = (float*)d_out;

    char* ws = (char*)d_ws;
    size_t off = 0;
    int* top_expert  = (int*)(ws + off); off += (size_t)N_TOK * 4;
    int* blockCounts = (int*)(ws + off); off += 256 * 16 * 4;
    int* blockOffs   = (int*)(ws + off); off += 256 * 16 * 4;
    int* totals      = (int*)(ws + off); off += 256;
    int* slot_token  = (int*)(ws + off); off += (size_t)E_EXP * CAPE * 4;
    ushort* W1F      = (ushort*)(ws + off); off += (size_t)E_EXP * D_IN * H_DIM * 2;
    ushort* W2F      = (ushort*)(ws + off); off += (size_t)E_EXP * H_DIM * O_DIM * 2;
    ushort* WgF      = (ushort*)(ws + off); off += (size_t)3 * GHID * D_IN * 2;

    wpack_all<<<4160, 64, 0, stream>>>(Wg1, WgF, W1, W1F, W2, W2F, blockCounts);
    gating_mfma_kernel<<<N_TOK / 128, 256, 0, stream>>>(x, WgF, bg1, Wg2, bg2, top_expert, blockCounts);
    scan_kernel<<<1, 256, 0, stream>>>(blockCounts, blockOffs, totals);
    scatter_kernel<<<N_TOK / 512, 64, 0, stream>>>(top_expert, blockOffs, slot_token, out);
    expert_mfma_kernel<<<E_EXP * (CAPE / 64), 512, 0, stream>>>(x, W1F, b1, W2F, b2, slot_token, totals, out);
}